// Round 8
// baseline (1072.775 us; speedup 1.0000x reference)
//
#include <hip/hip_runtime.h>
#include <math.h>

// Sinkhorn-divergence margin loss, MI355X.
// Scaled domain: F = f/(eps*ln2), M = C/(eps*ln2); softmin via exp2/log2.
// Ragged prefix mask exploited with wave-uniform skips.
// HARD CONSTRAINT (R2-R7 evidence): allocator budgets 64 VGPR for these kernels;
// keep per-thread live floats <= ~55 or it spills to scratch.
#define NL 256
#define ND 300
#define NC 5
#define NR 50

constexpr float SCf  = 577.07801635558534f;     // 1/(eps*ln2), eps=0.0025
constexpr float ELNf = 0.0017328679513998632f;  // eps*ln2
constexpr float BL2f = -5.6438561897747247f;    // log2(1/50)
constexpr float NEGB = -1.0e9f;
constexpr float MNEG = -3.0e38f;

// workspace layout (floats)
#define WS_XN   0        // 65536
#define WS_AL2  65536    // 65536
#define WS_YN   131072   // 256
#define WS_PA   131328   // 256
#define WS_QC   131584   // 16
#define WS_S    131600   // 1280

__device__ __forceinline__ float ex2(float x){ return __builtin_amdgcn_exp2f(x); }
__device__ __forceinline__ float lg2(float x){ return __builtin_amdgcn_logf(x); } // v_log_f32 = log2

// ---------------- k_pre: norms (scaled) + log2-weights ----------------
__global__ __launch_bounds__(256) void k_pre(const float* __restrict__ anchor,
                                             const float* __restrict__ weight,
                                             const float* __restrict__ t0,
                                             const int* __restrict__ lena,
                                             float* __restrict__ ws){
  const int blk=blockIdx.x, t=threadIdx.x;
  if(blk<256){
    const int len=lena[blk];
    const int lenS=(len+63)&~63;
    const int r=blk*256+t;
    if(t<lenS){
      const float4* row=(const float4*)(anchor+(size_t)r*ND);
      float s=0.f;
      #pragma unroll
      for(int k=0;k<75;k++){ float4 v=row[k];
        s=fmaf(v.x,v.x,fmaf(v.y,v.y,fmaf(v.z,v.z,fmaf(v.w,v.w,s)))); }
      ws[WS_XN+r]=0.5f*SCf*s;
    }
    const float w=weight[r];
    ws[WS_AL2+r]=(w>0.f)?log2f(w):NEGB;
  } else if(t<NC*NR){
    const float4* row=(const float4*)(t0+(size_t)t*ND);
    float s=0.f;
    #pragma unroll
    for(int k=0;k<75;k++){ float4 v=row[k];
      s=fmaf(v.x,v.x,fmaf(v.y,v.y,fmaf(v.z,v.z,fmaf(v.w,v.w,s)))); }
    ws[WS_YN+t]=0.5f*SCf*s;
  }
}

// ---------------- k_ab: blocks 0..4 -> q per c; 5..260 -> p per b ---------------- (unchanged R7)
__global__ __launch_bounds__(1024)
void k_ab(const float* __restrict__ anchor,
          const float* __restrict__ weight,
          const float* __restrict__ t0,
          const int* __restrict__ lena,
          float* __restrict__ ws){
  __shared__ __align__(16) float POOL[40544];   // 162176 B <= 160 KiB
  const int blk=blockIdx.x, t=threadIdx.x;
  if(blk>=5){
    float4* ML4=(float4*)POOL;                  // [1024 thr][8 f4], swizzled
    float4* xt4=(float4*)(POOL+32768);          // 1288 f4 x-tile
    float*  xnL=POOL+32768+5152;                // 256
    float*  HpP=xnL+256;                        // 4*68
    float*  PM =HpP+272;                        // 4*260
    float*  PS =PM+1040;                        // 4*260
    float*  red=PS+1040;                        // 16
    const int b=blk-5;
    const int len=lena[b];
    const int lenS=(len+63)&~63;
    const int i=t&255, h=t>>8;
    const float* xb=anchor+(size_t)b*NL*ND;
    if(t<256) xnL[t]=ws[WS_XN+b*256+t];
    const float al2=ws[WS_AL2+b*256+i];
    if(t<256) HpP[(t>>6)*68+(t&63)]=al2;        // P=0 init; rows>=len keep -1e9
    for(int e=t;e<1040;e+=1024){ PM[e]=MNEG; PS[e]=0.f; }
    const bool act=(i<len)&&(h*64<len);
    // staging indices
    const int r0=t/5, d40=t-r0*5;
    const bool st0=(r0<lenS);
    const int e1=t+1024, r1=e1/5, d41=e1-r1*5;
    const bool st1=(e1<1280)&&(r1<lenS);
    const float* g0p=xb+(size_t)r0*ND+d40*4;
    const float* g1p=xb+(size_t)r1*ND+d41*4;
    const int u0=5*r0+2*(r0>>6)+d40;
    const int u1=5*r1+2*(r1>>6)+d41;
    const int cb=322*h;                         // col-chunk base in xt4
    const int xti=5*i+2*(i>>6);                 // own-row base in xt4
    const int ub=t*8;                           // own ML4 region (8 units)
    const int sw=i&7;                           // ML swizzle
    float Mr[32];
    float Pi=0.f;
    #pragma unroll 1
    for(int pass=0;pass<2;pass++){
      const int KOFF=(pass==0)?0:32;
      #pragma unroll
      for(int k=0;k<32;k++) Mr[k]=0.f;
      float4 pf0,pf1;
      if(st0) pf0=*(const float4*)(g0p);
      if(st1) pf1=*(const float4*)(g1p);
      #pragma unroll 1
      for(int tile=0;tile<15;tile++){
        __syncthreads();
        if(st0) xt4[u0]=pf0;
        if(st1) xt4[u1]=pf1;
        __syncthreads();
        if(tile<14){
          if(st0) pf0=*(const float4*)(g0p+(tile+1)*20);
          if(st1) pf1=*(const float4*)(g1p+(tile+1)*20);
        }
        if(act){
          #pragma unroll 1
          for(int d4=0;d4<5;d4++){
            const float4 xq=xt4[xti+d4];        // own row from staged tile
            #pragma unroll
            for(int kk=0;kk<32;kk++){
              const float4 yv=xt4[cb+5*(KOFF+kk)+d4];  // wave-uniform broadcast
              Mr[kk]=fmaf(xq.x,yv.x,fmaf(xq.y,yv.y,fmaf(xq.z,yv.z,fmaf(xq.w,yv.w,Mr[kk]))));
            }
          }
        }
      }
      if(act){
        const float xni=xnL[i];
        #pragma unroll
        for(int kk=0;kk<32;kk++) Mr[kk]=xni+xnL[64*h+KOFF+kk]-SCf*Mr[kk];
      }
      if(pass==0){
        #pragma unroll
        for(int q4=0;q4<8;q4++){
          float4 v; v.x=Mr[4*q4+0]; v.y=Mr[4*q4+1]; v.z=Mr[4*q4+2]; v.w=Mr[4*q4+3];
          ML4[ub+(q4^sw)]=v;                    // private region, no barrier needed
        }
      }
    }
    __syncthreads();
    const float* Hh=&HpP[h*68];
    #pragma unroll 1
    for(int it=0; it<51; ++it){
      if(act){
        float m0=MNEG,m1=MNEG,m2=MNEG,m3=MNEG;
        #pragma unroll
        for(int q4=0;q4<8;q4++){                // reg half: cols 64h+32+...
          const float4 hv=*(const float4*)&Hh[32+4*q4];
          m0=fmaxf(m0,hv.x-Mr[4*q4+0]); m1=fmaxf(m1,hv.y-Mr[4*q4+1]);
          m2=fmaxf(m2,hv.z-Mr[4*q4+2]); m3=fmaxf(m3,hv.w-Mr[4*q4+3]);
        }
        #pragma unroll
        for(int q4=0;q4<8;q4++){                // LDS half: cols 64h+...
          const float4 mv=ML4[ub+(q4^sw)];
          const float4 hv=*(const float4*)&Hh[4*q4];
          m0=fmaxf(m0,hv.x-mv.x); m1=fmaxf(m1,hv.y-mv.y);
          m2=fmaxf(m2,hv.z-mv.z); m3=fmaxf(m3,hv.w-mv.w);
        }
        const float m=fmaxf(fmaxf(m0,m1),fmaxf(m2,m3));
        float s0=0.f,s1=0.f,s2=0.f,s3=0.f;
        #pragma unroll
        for(int q4=0;q4<8;q4++){
          const float4 hv=*(const float4*)&Hh[32+4*q4];
          s0+=ex2(hv.x-Mr[4*q4+0]-m); s1+=ex2(hv.y-Mr[4*q4+1]-m);
          s2+=ex2(hv.z-Mr[4*q4+2]-m); s3+=ex2(hv.w-Mr[4*q4+3]-m);
        }
        #pragma unroll
        for(int q4=0;q4<8;q4++){
          const float4 mv=ML4[ub+(q4^sw)];
          const float4 hv=*(const float4*)&Hh[4*q4];
          s0+=ex2(hv.x-mv.x-m); s1+=ex2(hv.y-mv.y-m);
          s2+=ex2(hv.z-mv.z-m); s3+=ex2(hv.w-mv.w-m);
        }
        PM[h*260+i]=m;
        PS[h*260+i]=(s0+s1)+(s2+s3);
      }
      __syncthreads();
      if(t<256 && t<len){                       // combine 4 chunk-partials, update H
        const float p0=PM[t],p1=PM[260+t],p2=PM[520+t],p3=PM[780+t];
        const float mm=fmaxf(fmaxf(p0,p1),fmaxf(p2,p3));
        const float ssv=PS[t]*ex2(p0-mm)+PS[260+t]*ex2(p1-mm)
                       +PS[520+t]*ex2(p2-mm)+PS[780+t]*ex2(p3-mm);
        const float sm=-(mm+lg2(ssv));
        Pi=(it==0)?sm:0.5f*(Pi+sm);
        HpP[(t>>6)*68+(t&63)]=al2+Pi;
      }
      __syncthreads();
    }
    float cv=(t<256 && t<len)?(weight[(size_t)b*256+t]*Pi):0.f;
    #pragma unroll
    for(int off=1;off<64;off<<=1) cv+=__shfl_xor(cv,off);
    if((t&63)==0) red[t>>6]=cv;
    __syncthreads();
    if(t==0){ float ss=0.f;
      #pragma unroll
      for(int k2=0;k2<16;k2++) ss+=red[k2];
      ws[WS_PA+b]=ELNf*ss; }
  } else {
    // -------- q per c (50x50), 2 thr/row: My[25] --------
    float* MyL =POOL;          // 50*52
    float* QL  =POOL+2600;     // 64
    float* redq=POOL+2664;     // 2
    const int c=blk;
    const float* yc=t0+(size_t)c*NR*ND;
    #pragma unroll 1
    for(int rr=0;rr<3;rr++){
      const int o=t+1024*rr;
      if(o<2500){
        const int j=o/50, k=o-j*50;
        const float4* a4=(const float4*)(yc+(size_t)j*ND);
        const float4* b4=(const float4*)(yc+(size_t)k*ND);
        float s=0.f;
        #pragma unroll
        for(int d4=0;d4<75;d4++){ const float4 av=a4[d4],bv=b4[d4];
          s=fmaf(av.x,bv.x,fmaf(av.y,bv.y,fmaf(av.z,bv.z,fmaf(av.w,bv.w,s)))); }
        MyL[j*52+k]=ws[WS_YN+c*50+j]+ws[WS_YN+c*50+k]-SCf*s;
      }
    }
    if(t<64) QL[t]=0.f;
    __syncthreads();
    const int j=t>>1, h2=t&1;
    float My[25]; float Qj=0.f;
    if(t<100){
      #pragma unroll
      for(int m=0;m<25;m++) My[m]=MyL[j*52+2*m+h2];
    }
    #pragma unroll 1
    for(int it=0; it<51; ++it){
      float sm=0.f;
      if(t<100){
        float mx=MNEG;
        #pragma unroll
        for(int m=0;m<25;m++) mx=fmaxf(mx,BL2f+QL[2*m+h2]-My[m]);
        mx=fmaxf(mx,__shfl_xor(mx,1));
        float s=0.f;
        #pragma unroll
        for(int m=0;m<25;m++) s+=ex2(BL2f+QL[2*m+h2]-My[m]-mx);
        s+=__shfl_xor(s,1);
        sm=-(mx+lg2(s));
      }
      __syncthreads();
      if(t<100){ Qj=(it==0)?sm:0.5f*(Qj+sm); if(h2==0) QL[j]=Qj; }
      __syncthreads();
    }
    float cv=(t<100&&h2==0)?Qj:0.f;
    #pragma unroll
    for(int off=1;off<64;off<<=1) cv+=__shfl_xor(cv,off);
    if(t==0)  redq[0]=cv;
    if(t==64) redq[1]=cv;
    __syncthreads();
    if(t==0) ws[WS_QC+c]=ELNf*0.02f*(redq[0]+redq[1]);
  }
}

// ---------------- k_c: f,g per (b,c); 1024 thr, dedicated wave roles ----------------
// waves 0..7  (f): 2 thr/row (i=t>>1,h=t&1), 25 cols in regs from GEMM; wave w covers rows [32w,32w+32)
// waves 8..15 (g): wave -> 32-row chunk = ((w-8)+6)&7 (rotation balances SIMDs at partial len);
//                  lane = col; M^T read from MT4[unit][col] (16B lane stride: conflict-free b128)
// upper waves double-buffer y-tile staging during GEMM; combine in wave 10 (chunk 0) only.
__global__ __launch_bounds__(1024)
void k_c(const float* __restrict__ anchor,
         const float* __restrict__ weight,
         const float* __restrict__ t0,
         const int* __restrict__ lena,
         float* __restrict__ ws){
  __shared__ __align__(16) float4 MT4[64*52];  // [unit u=row/4][col j]; elem comp = row&3 ; 53248B
  __shared__ __align__(16) float yt[2][1000];  // double-buffered y-tile [50][20]
  __shared__ float ynL[52];
  __shared__ __align__(16) float AfP[8*40];    // al2+F: row r -> (r>>5)*40+(r&31)
  __shared__ float GLb[52];                    // BL2f + G
  __shared__ float PM[8*52];
  __shared__ float PS[8*52];
  __shared__ float red[10];
  const int blk=blockIdx.x, t=threadIdx.x;
  const int c=blk>>8, b=blk&255;
  const int len=lena[b];
  const int w=t>>6, l=t&63;
  const int i=t>>1, h=t&1;                     // f mapping (t<512)
  const int iA=i&255;
  const float* xb=anchor+(size_t)b*NL*ND;
  const float* yc=t0+(size_t)c*NR*ND;
  if(t<50){ ynL[t]=ws[WS_YN+c*50+t]; GLb[t]=BL2f; }
  if(t<416){ PM[t]=MNEG; PS[t]=0.f; }
  const float al2=ws[WS_AL2+b*256+iA];
  if(t<512 && h==0) AfP[(i>>5)*40+(i&31)]=al2; // F=0 init; rows>=len hold -1e9
  // staging setup (upper waves)
  const int st=t-512;
  const int sr=(st>=0&&st<250)?(st/5):0, sd=(st>=0&&st<250)?(st-(st/5)*5):0;
  const bool stg=(t>=512)&&(st<250);
  const float* gsp=yc+(size_t)sr*ND+sd*4;
  if(stg) *(float4*)&yt[0][sr*20+sd*4]=*(const float4*)gsp;
  float Mr[25];
  #pragma unroll
  for(int k=0;k<25;k++) Mr[k]=0.f;
  const bool fComp=(t<512)&&(i<len);
  __syncthreads();
  #pragma unroll 1
  for(int tile=0;tile<15;tile++){
    if(fComp){
      const float4* xrow=(const float4*)(xb+(size_t)i*ND+tile*20);
      const float4 xq0=xrow[0],xq1=xrow[1],xq2=xrow[2],xq3=xrow[3],xq4=xrow[4];
      const float* ytc=yt[tile&1];
      #pragma unroll
      for(int k=0;k<25;k++){
        const int j=2*k+h;
        const float4 y0=*(const float4*)&ytc[j*20+0];
        const float4 y1=*(const float4*)&ytc[j*20+4];
        const float4 y2=*(const float4*)&ytc[j*20+8];
        const float4 y3=*(const float4*)&ytc[j*20+12];
        const float4 y4=*(const float4*)&ytc[j*20+16];
        float acc=Mr[k];
        acc=fmaf(xq0.x,y0.x,fmaf(xq0.y,y0.y,fmaf(xq0.z,y0.z,fmaf(xq0.w,y0.w,acc))));
        acc=fmaf(xq1.x,y1.x,fmaf(xq1.y,y1.y,fmaf(xq1.z,y1.z,fmaf(xq1.w,y1.w,acc))));
        acc=fmaf(xq2.x,y2.x,fmaf(xq2.y,y2.y,fmaf(xq2.z,y2.z,fmaf(xq2.w,y2.w,acc))));
        acc=fmaf(xq3.x,y3.x,fmaf(xq3.y,y3.y,fmaf(xq3.z,y3.z,fmaf(xq3.w,y3.w,acc))));
        acc=fmaf(xq4.x,y4.x,fmaf(xq4.y,y4.y,fmaf(xq4.z,y4.z,fmaf(xq4.w,y4.w,acc))));
        Mr[k]=acc;
      }
    }
    if(stg && tile<14) *(float4*)&yt[(tile+1)&1][sr*20+sd*4]=*(const float4*)(gsp+(tile+1)*20);
    __syncthreads();
  }
  if(fComp){
    const float xni=ws[WS_XN+b*256+i];
    #pragma unroll
    for(int k=0;k<25;k++) Mr[k]=xni+ynL[2*k+h]-SCf*Mr[k];
  }
  if(t<512){ // transpose into MT4 (rows>=len write 0: finite; masked via AfP=-1e9)
    #pragma unroll
    for(int k=0;k<25;k++){
      ((float*)&MT4[(i>>2)*52+(2*k+h)])[i&3]=Mr[k];
    }
  }
  __syncthreads();
  float Fi=0.f, Gj=0.f;
  const int chunk=((w-8)+6)&7;                 // g-role chunk (wave 10 -> chunk 0)
  const bool fWave=(w<8)&&((w<<5)<len);
  const bool gWave=(w>=8)&&((chunk<<5)<len);
  const bool gAct=gWave&&(l<50);
  #pragma unroll 1
  for(int it=0; it<51; ++it){
    float smf=0.f;
    if(fWave){
      float m0=MNEG,m1=MNEG,m2=MNEG,m3=MNEG;
      #pragma unroll
      for(int k=0;k<24;k+=4){
        m0=fmaxf(m0,GLb[2*k+h]-Mr[k+0]);   m1=fmaxf(m1,GLb[2*k+2+h]-Mr[k+1]);
        m2=fmaxf(m2,GLb[2*k+4+h]-Mr[k+2]); m3=fmaxf(m3,GLb[2*k+6+h]-Mr[k+3]);
      }
      m0=fmaxf(m0,GLb[48+h]-Mr[24]);
      float mf=fmaxf(fmaxf(m0,m1),fmaxf(m2,m3));
      mf=fmaxf(mf,__shfl_xor(mf,1));
      float s0=0.f,s1=0.f,s2=0.f,s3=0.f;
      #pragma unroll
      for(int k=0;k<24;k+=4){
        s0+=ex2(GLb[2*k+h]-Mr[k+0]-mf);   s1+=ex2(GLb[2*k+2+h]-Mr[k+1]-mf);
        s2+=ex2(GLb[2*k+4+h]-Mr[k+2]-mf); s3+=ex2(GLb[2*k+6+h]-Mr[k+3]-mf);
      }
      s0+=ex2(GLb[48+h]-Mr[24]-mf);
      float fs=(s0+s1)+(s2+s3);
      fs+=__shfl_xor(fs,1);
      smf=-(mf+lg2(fs));
    } else if(gAct){
      const int ub=chunk*8;
      float g0=MNEG,g1=MNEG,g2=MNEG,g3=MNEG;
      #pragma unroll
      for(int r4=0;r4<8;r4++){
        const float4 mv=MT4[(ub+r4)*52+l];
        const float4 av=*(const float4*)&AfP[chunk*40+4*r4];
        g0=fmaxf(g0,av.x-mv.x); g1=fmaxf(g1,av.y-mv.y);
        g2=fmaxf(g2,av.z-mv.z); g3=fmaxf(g3,av.w-mv.w);
      }
      const float gm=fmaxf(fmaxf(g0,g1),fmaxf(g2,g3));
      float s0=0.f,s1=0.f,s2=0.f,s3=0.f;
      #pragma unroll
      for(int r4=0;r4<8;r4++){
        const float4 mv=MT4[(ub+r4)*52+l];
        const float4 av=*(const float4*)&AfP[chunk*40+4*r4];
        s0+=ex2(av.x-mv.x-gm); s1+=ex2(av.y-mv.y-gm);
        s2+=ex2(av.z-mv.z-gm); s3+=ex2(av.w-mv.w-gm);
      }
      PM[chunk*52+l]=gm;
      PS[chunk*52+l]=(s0+s1)+(s2+s3);
    }
    __syncthreads();
    if(fWave){
      Fi=(it==0)?smf:0.5f*(Fi+smf);
      if(h==0 && i<len) AfP[(i>>5)*40+(i&31)]=al2+Fi;
    }
    if(w==10 && l<50){                          // chunk-0 wave combines 8 partials
      float mm=MNEG;
      float p0=PM[l],p1=PM[52+l],p2=PM[104+l],p3=PM[156+l];
      float p4=PM[208+l],p5=PM[260+l],p6=PM[312+l],p7=PM[364+l];
      mm=fmaxf(fmaxf(fmaxf(p0,p1),fmaxf(p2,p3)),fmaxf(fmaxf(p4,p5),fmaxf(p6,p7)));
      float ssv=PS[l]*ex2(p0-mm)+PS[52+l]*ex2(p1-mm)
               +PS[104+l]*ex2(p2-mm)+PS[156+l]*ex2(p3-mm)
               +PS[208+l]*ex2(p4-mm)+PS[260+l]*ex2(p5-mm)
               +PS[312+l]*ex2(p6-mm)+PS[364+l]*ex2(p7-mm);
      const float smg=-(mm+lg2(ssv));
      Gj=(it==0)?smg:0.5f*(Gj+smg);
      GLb[l]=BL2f+Gj;
    }
    __syncthreads();
  }
  // S[b,c] = ELN*(sum_i a_i F_i + 0.02*sum_j G_j)
  float cv=(t<512 && h==0 && i<len)?(weight[(size_t)b*256+i]*Fi):0.f;
  #pragma unroll
  for(int off=1;off<64;off<<=1) cv+=__shfl_xor(cv,off);
  if(w<8 && l==0) red[w]=cv;
  if(w==10){
    float gv=(l<50)?Gj:0.f;
    #pragma unroll
    for(int off=1;off<64;off<<=1) gv+=__shfl_xor(gv,off);
    if(l==0) red[8]=gv;
  }
  __syncthreads();
  if(t==0){
    float sa=red[0]+red[1]+red[2]+red[3]+red[4]+red[5]+red[6]+red[7];
    ws[WS_S+b*NC+c]=ELNf*(sa+0.02f*red[8]);
  }
}

// ---------------- k_d: margin loss + mean ----------------
__global__ __launch_bounds__(256) void k_d(const int* __restrict__ grade,
                                           const float* __restrict__ ws,
                                           float* __restrict__ out){
  __shared__ float red[4];
  const int t=threadIdx.x;
  const int g=grade[t];
  const float pa=ws[WS_PA+t];
  const float d0=ws[WS_S+t*NC+0]-pa-ws[WS_QC+0];
  const float d1=ws[WS_S+t*NC+1]-pa-ws[WS_QC+1];
  const float d2=ws[WS_S+t*NC+2]-pa-ws[WS_QC+2];
  const float d3=ws[WS_S+t*NC+3]-pa-ws[WS_QC+3];
  const float d4=ws[WS_S+t*NC+4]-pa-ws[WS_QC+4];
  const float pos=(g==0)?d0:(g==1)?d1:(g==2)?d2:(g==3)?d3:d4;
  float loss=0.f;
  if(g!=0) loss+=fmaxf(0.f,pos-d0+10.f);
  if(g!=1) loss+=fmaxf(0.f,pos-d1+10.f);
  if(g!=2) loss+=fmaxf(0.f,pos-d2+10.f);
  if(g!=3) loss+=fmaxf(0.f,pos-d3+10.f);
  if(g!=4) loss+=fmaxf(0.f,pos-d4+10.f);
  loss*=0.2f;
  #pragma unroll
  for(int off=1;off<64;off<<=1) loss+=__shfl_xor(loss,off);
  if((t&63)==0) red[t>>6]=loss;
  __syncthreads();
  if(t==0) out[0]=(red[0]+red[1]+red[2]+red[3])*(1.f/256.f);
}

extern "C" void kernel_launch(void* const* d_in, const int* in_sizes, int n_in,
                              void* d_out, int out_size, void* d_ws, size_t ws_size,
                              hipStream_t stream){
  (void)in_sizes;(void)n_in;(void)out_size;(void)ws_size;
  const float* anchor=(const float*)d_in[0];
  const float* weight=(const float*)d_in[1];
  const float* t0    =(const float*)d_in[2];
  const int*   lena  =(const int*)d_in[4];
  const int*   grade =(const int*)d_in[5];
  float* ws=(float*)d_ws;
  float* out=(float*)d_out;
  k_pre<<<257,256,0,stream>>>(anchor,weight,t0,lena,ws);
  k_ab <<<261,1024,0,stream>>>(anchor,weight,t0,lena,ws);
  k_c  <<<1280,1024,0,stream>>>(anchor,weight,t0,lena,ws);
  k_d  <<<1,256,0,stream>>>(grade,ws,out);
}

// Round 9
// 954.245 us; speedup vs baseline: 1.1242x; 1.1242x over previous
//
#include <hip/hip_runtime.h>
#include <math.h>

// Sinkhorn-divergence margin loss, MI355X.
// Scaled domain: F = f/(eps*ln2), M = C/(eps*ln2); softmin via exp2/log2.
// Ragged prefix mask exploited with wave-uniform skips.
// HARD CONSTRAINT (R2-R8): allocator budgets 64 VGPR here; keep live floats <= ~55.
// LDS RULE (R8 post-mortem): lane-indexed reads need 16B lane stride ([unit][lane]);
// any t*2^k element stride aliases banks (R7 MTg4, R7/R8 ML4 were 8-way conflicted).
#define NL 256
#define ND 300
#define NC 5
#define NR 50

constexpr float SCf  = 577.07801635558534f;     // 1/(eps*ln2), eps=0.0025
constexpr float ELNf = 0.0017328679513998632f;  // eps*ln2
constexpr float BL2f = -5.6438561897747247f;    // log2(1/50)
constexpr float NEGB = -1.0e9f;
constexpr float MNEG = -3.0e38f;

// workspace layout (floats)
#define WS_XN   0        // 65536
#define WS_AL2  65536    // 65536
#define WS_YN   131072   // 256
#define WS_PA   131328   // 256
#define WS_QC   131584   // 16
#define WS_S    131600   // 1280

__device__ __forceinline__ float ex2(float x){ return __builtin_amdgcn_exp2f(x); }
__device__ __forceinline__ float lg2(float x){ return __builtin_amdgcn_logf(x); } // v_log_f32 = log2

// ---------------- k_pre: norms (scaled) + log2-weights ----------------
__global__ __launch_bounds__(256) void k_pre(const float* __restrict__ anchor,
                                             const float* __restrict__ weight,
                                             const float* __restrict__ t0,
                                             const int* __restrict__ lena,
                                             float* __restrict__ ws){
  const int blk=blockIdx.x, t=threadIdx.x;
  if(blk<256){
    const int len=lena[blk];
    const int lenS=(len+63)&~63;
    const int r=blk*256+t;
    if(t<lenS){
      const float4* row=(const float4*)(anchor+(size_t)r*ND);
      float s=0.f;
      #pragma unroll
      for(int k=0;k<75;k++){ float4 v=row[k];
        s=fmaf(v.x,v.x,fmaf(v.y,v.y,fmaf(v.z,v.z,fmaf(v.w,v.w,s)))); }
      ws[WS_XN+r]=0.5f*SCf*s;
    }
    const float w=weight[r];
    ws[WS_AL2+r]=(w>0.f)?log2f(w):NEGB;
  } else if(t<NC*NR){
    const float4* row=(const float4*)(t0+(size_t)t*ND);
    float s=0.f;
    #pragma unroll
    for(int k=0;k<75;k++){ float4 v=row[k];
      s=fmaf(v.x,v.x,fmaf(v.y,v.y,fmaf(v.z,v.z,fmaf(v.w,v.w,s)))); }
    ws[WS_YN+t]=0.5f*SCf*s;
  }
}

// ---------------- k_ab: blocks 0..4 -> q per c; 5..260 -> p per b ----------------
// p: thread (i=t&255, h=t>>8) owns cols [64h,64h+64): 32 in LDS (pass A), 32 in regs (pass B).
// ML4 layout [q4][1024 threads]: lane stride 16B -> conflict-free (R9 fix).
__global__ __launch_bounds__(1024)
void k_ab(const float* __restrict__ anchor,
          const float* __restrict__ weight,
          const float* __restrict__ t0,
          const int* __restrict__ lena,
          float* __restrict__ ws){
  __shared__ __align__(16) float POOL[40544];   // 162176 B <= 160 KiB
  const int blk=blockIdx.x, t=threadIdx.x;
  if(blk>=5){
    float4* ML4=(float4*)POOL;                  // [8 q4][1024 thr]
    float4* xt4=(float4*)(POOL+32768);          // 1288 f4 x-tile
    float*  xnL=POOL+32768+5152;                // 256
    float*  HpP=xnL+256;                        // 4*68
    float*  PM =HpP+272;                        // 4*260
    float*  PS =PM+1040;                        // 4*260
    float*  red=PS+1040;                        // 16
    const int b=blk-5;
    const int len=lena[b];
    const int lenS=(len+63)&~63;
    const int i=t&255, h=t>>8;
    const float* xb=anchor+(size_t)b*NL*ND;
    if(t<256) xnL[t]=ws[WS_XN+b*256+t];
    const float al2=ws[WS_AL2+b*256+i];
    if(t<256) HpP[(t>>6)*68+(t&63)]=al2;        // P=0 init; rows>=len keep -1e9
    for(int e=t;e<1040;e+=1024){ PM[e]=MNEG; PS[e]=0.f; }
    const bool act=(i<len)&&(h*64<len);
    // staging indices
    const int r0=t/5, d40=t-r0*5;
    const bool st0=(r0<lenS);
    const int e1=t+1024, r1=e1/5, d41=e1-r1*5;
    const bool st1=(e1<1280)&&(r1<lenS);
    const float* g0p=xb+(size_t)r0*ND+d40*4;
    const float* g1p=xb+(size_t)r1*ND+d41*4;
    const int u0=5*r0+2*(r0>>6)+d40;
    const int u1=5*r1+2*(r1>>6)+d41;
    const int cb=322*h;                         // col-chunk base in xt4
    const int xti=5*i+2*(i>>6);                 // own-row base in xt4
    float Mr[32];
    float Pi=0.f;
    #pragma unroll 1
    for(int pass=0;pass<2;pass++){
      const int KOFF=(pass==0)?0:32;
      #pragma unroll
      for(int k=0;k<32;k++) Mr[k]=0.f;
      float4 pf0,pf1;
      if(st0) pf0=*(const float4*)(g0p);
      if(st1) pf1=*(const float4*)(g1p);
      #pragma unroll 1
      for(int tile=0;tile<15;tile++){
        __syncthreads();
        if(st0) xt4[u0]=pf0;
        if(st1) xt4[u1]=pf1;
        __syncthreads();
        if(tile<14){
          if(st0) pf0=*(const float4*)(g0p+(tile+1)*20);
          if(st1) pf1=*(const float4*)(g1p+(tile+1)*20);
        }
        if(act){
          #pragma unroll 1
          for(int d4=0;d4<5;d4++){
            const float4 xq=xt4[xti+d4];        // own row from staged tile
            #pragma unroll
            for(int kk=0;kk<32;kk++){
              const float4 yv=xt4[cb+5*(KOFF+kk)+d4];  // wave-uniform broadcast
              Mr[kk]=fmaf(xq.x,yv.x,fmaf(xq.y,yv.y,fmaf(xq.z,yv.z,fmaf(xq.w,yv.w,Mr[kk]))));
            }
          }
        }
      }
      if(act){
        const float xni=xnL[i];
        #pragma unroll
        for(int kk=0;kk<32;kk++) Mr[kk]=xni+xnL[64*h+KOFF+kk]-SCf*Mr[kk];
      }
      if(pass==0){
        #pragma unroll
        for(int q4=0;q4<8;q4++){
          float4 v; v.x=Mr[4*q4+0]; v.y=Mr[4*q4+1]; v.z=Mr[4*q4+2]; v.w=Mr[4*q4+3];
          ML4[q4*1024+t]=v;                     // [q4][t]: conflict-free
        }
      }
    }
    __syncthreads();
    const float* Hh=&HpP[h*68];
    #pragma unroll 1
    for(int it=0; it<51; ++it){
      if(act){
        float m0=MNEG,m1=MNEG,m2=MNEG,m3=MNEG;
        #pragma unroll
        for(int q4=0;q4<8;q4++){                // reg half: cols 64h+32+...
          const float4 hv=*(const float4*)&Hh[32+4*q4];
          m0=fmaxf(m0,hv.x-Mr[4*q4+0]); m1=fmaxf(m1,hv.y-Mr[4*q4+1]);
          m2=fmaxf(m2,hv.z-Mr[4*q4+2]); m3=fmaxf(m3,hv.w-Mr[4*q4+3]);
        }
        #pragma unroll
        for(int q4=0;q4<8;q4++){                // LDS half: cols 64h+...
          const float4 mv=ML4[q4*1024+t];
          const float4 hv=*(const float4*)&Hh[4*q4];
          m0=fmaxf(m0,hv.x-mv.x); m1=fmaxf(m1,hv.y-mv.y);
          m2=fmaxf(m2,hv.z-mv.z); m3=fmaxf(m3,hv.w-mv.w);
        }
        const float m=fmaxf(fmaxf(m0,m1),fmaxf(m2,m3));
        float s0=0.f,s1=0.f,s2=0.f,s3=0.f;
        #pragma unroll
        for(int q4=0;q4<8;q4++){
          const float4 hv=*(const float4*)&Hh[32+4*q4];
          s0+=ex2(hv.x-Mr[4*q4+0]-m); s1+=ex2(hv.y-Mr[4*q4+1]-m);
          s2+=ex2(hv.z-Mr[4*q4+2]-m); s3+=ex2(hv.w-Mr[4*q4+3]-m);
        }
        #pragma unroll
        for(int q4=0;q4<8;q4++){
          const float4 mv=ML4[q4*1024+t];
          const float4 hv=*(const float4*)&Hh[4*q4];
          s0+=ex2(hv.x-mv.x-m); s1+=ex2(hv.y-mv.y-m);
          s2+=ex2(hv.z-mv.z-m); s3+=ex2(hv.w-mv.w-m);
        }
        PM[h*260+i]=m;
        PS[h*260+i]=(s0+s1)+(s2+s3);
      }
      __syncthreads();
      if(t<256 && t<len){                       // combine 4 chunk-partials, update H
        const float p0=PM[t],p1=PM[260+t],p2=PM[520+t],p3=PM[780+t];
        const float mm=fmaxf(fmaxf(p0,p1),fmaxf(p2,p3));
        const float ssv=PS[t]*ex2(p0-mm)+PS[260+t]*ex2(p1-mm)
                       +PS[520+t]*ex2(p2-mm)+PS[780+t]*ex2(p3-mm);
        const float sm=-(mm+lg2(ssv));
        Pi=(it==0)?sm:0.5f*(Pi+sm);
        HpP[(t>>6)*68+(t&63)]=al2+Pi;
      }
      __syncthreads();
    }
    float cv=(t<256 && t<len)?(weight[(size_t)b*256+t]*Pi):0.f;
    #pragma unroll
    for(int off=1;off<64;off<<=1) cv+=__shfl_xor(cv,off);
    if((t&63)==0) red[t>>6]=cv;
    __syncthreads();
    if(t==0){ float ss=0.f;
      #pragma unroll
      for(int k2=0;k2<16;k2++) ss+=red[k2];
      ws[WS_PA+b]=ELNf*ss; }
  } else {
    // -------- q per c (50x50), 2 thr/row: My[25] --------
    float* MyL =POOL;          // 50*52
    float* QL  =POOL+2600;     // 64
    float* redq=POOL+2664;     // 2
    const int c=blk;
    const float* yc=t0+(size_t)c*NR*ND;
    #pragma unroll 1
    for(int rr=0;rr<3;rr++){
      const int o=t+1024*rr;
      if(o<2500){
        const int j=o/50, k=o-j*50;
        const float4* a4=(const float4*)(yc+(size_t)j*ND);
        const float4* b4=(const float4*)(yc+(size_t)k*ND);
        float s=0.f;
        #pragma unroll
        for(int d4=0;d4<75;d4++){ const float4 av=a4[d4],bv=b4[d4];
          s=fmaf(av.x,bv.x,fmaf(av.y,bv.y,fmaf(av.z,bv.z,fmaf(av.w,bv.w,s)))); }
        MyL[j*52+k]=ws[WS_YN+c*50+j]+ws[WS_YN+c*50+k]-SCf*s;
      }
    }
    if(t<64) QL[t]=0.f;
    __syncthreads();
    const int j=t>>1, h2=t&1;
    float My[25]; float Qj=0.f;
    if(t<100){
      #pragma unroll
      for(int m=0;m<25;m++) My[m]=MyL[j*52+2*m+h2];
    }
    #pragma unroll 1
    for(int it=0; it<51; ++it){
      float sm=0.f;
      if(t<100){
        float mx=MNEG;
        #pragma unroll
        for(int m=0;m<25;m++) mx=fmaxf(mx,BL2f+QL[2*m+h2]-My[m]);
        mx=fmaxf(mx,__shfl_xor(mx,1));
        float s=0.f;
        #pragma unroll
        for(int m=0;m<25;m++) s+=ex2(BL2f+QL[2*m+h2]-My[m]-mx);
        s+=__shfl_xor(s,1);
        sm=-(mx+lg2(s));
      }
      __syncthreads();
      if(t<100){ Qj=(it==0)?sm:0.5f*(Qj+sm); if(h2==0) QL[j]=Qj; }
      __syncthreads();
    }
    float cv=(t<100&&h2==0)?Qj:0.f;
    #pragma unroll
    for(int off=1;off<64;off<<=1) cv+=__shfl_xor(cv,off);
    if(t==0)  redq[0]=cv;
    if(t==64) redq[1]=cv;
    __syncthreads();
    if(t==0) ws[WS_QC+c]=ELNf*0.02f*(redq[0]+redq[1]);
  }
}

// ---------------- k_c: f,g per (b,c); 512 thr, merged roles (R7) + [unit][col] MT4 (R8) ----------------
// f: thread (i=t>>1,h=t&1) owns row i's 25 cols in regs (Mr), shfl-pair combine.
// g: wave w = row-chunk [32w,32w+32) (same rows as its f work -> one mask), lane l = col;
//    M^T read MT4[(w*8+r4)][l]: 16B lane stride, conflict-free, immediate offsets.
// combine: wave 0 only. 2 barriers/iter. LDS ~62KB -> 2 blocks/CU.
__global__ __launch_bounds__(512)
void k_c(const float* __restrict__ anchor,
         const float* __restrict__ weight,
         const float* __restrict__ t0,
         const int* __restrict__ lena,
         float* __restrict__ ws){
  __shared__ __align__(16) float4 MT4[64*52];  // [unit u=row/4][col j]; comp=row&3; 53248B
  __shared__ __align__(16) float yt[1000];     // y-tile [50][20]
  __shared__ float ynL[52];
  __shared__ __align__(16) float AfP[8*40];    // al2+F: row r -> (r>>5)*40+(r&31)
  __shared__ __align__(16) float GLbp[2][32];  // BL2f+G parity-split: col j -> [j&1][j>>1]
  __shared__ float PM[8*52];
  __shared__ float PS[8*52];
  __shared__ float red[9];
  const int blk=blockIdx.x, t=threadIdx.x;
  const int c=blk>>8, b=blk&255;
  const int len=lena[b];
  const int i=t>>1, h=t&1;
  const int w=t>>6, l=t&63;
  const bool rowAct=(i<len);
  const float* xb=anchor+(size_t)b*NL*ND;
  const float* yc=t0+(size_t)c*NR*ND;
  if(t<50) ynL[t]=ws[WS_YN+c*50+t];
  if(t<64) GLbp[t>>5][t&31]=BL2f;
  if(t<416){ PM[t]=MNEG; PS[t]=0.f; }
  const float al2=ws[WS_AL2+b*256+i];
  if(h==0) AfP[(i>>5)*40+(i&31)]=al2;          // F=0 init; rows>=len hold -1e9
  float Mr[25];
  #pragma unroll
  for(int k=0;k<25;k++) Mr[k]=0.f;
  // staging (reg-prefetch)
  const int sr=(t<250)?(t/5):0, sd=(t<250)?(t-(t/5)*5):0;
  const bool stg=(t<250);
  const float* gsp=yc+(size_t)sr*ND+sd*4;
  float4 pf;
  if(stg) pf=*(const float4*)gsp;
  #pragma unroll 1
  for(int tile=0;tile<15;tile++){
    __syncthreads();
    if(stg) *(float4*)&yt[sr*20+sd*4]=pf;
    __syncthreads();
    if(tile<14 && stg) pf=*(const float4*)(gsp+(tile+1)*20);
    if(rowAct){
      const float4* xrow=(const float4*)(xb+(size_t)i*ND+tile*20);
      const float4 xq0=xrow[0],xq1=xrow[1],xq2=xrow[2],xq3=xrow[3],xq4=xrow[4];
      #pragma unroll
      for(int k=0;k<25;k++){
        const int j=2*k+h;
        const float4 y0=*(const float4*)&yt[j*20+0];
        const float4 y1=*(const float4*)&yt[j*20+4];
        const float4 y2=*(const float4*)&yt[j*20+8];
        const float4 y3=*(const float4*)&yt[j*20+12];
        const float4 y4=*(const float4*)&yt[j*20+16];
        float acc=Mr[k];
        acc=fmaf(xq0.x,y0.x,fmaf(xq0.y,y0.y,fmaf(xq0.z,y0.z,fmaf(xq0.w,y0.w,acc))));
        acc=fmaf(xq1.x,y1.x,fmaf(xq1.y,y1.y,fmaf(xq1.z,y1.z,fmaf(xq1.w,y1.w,acc))));
        acc=fmaf(xq2.x,y2.x,fmaf(xq2.y,y2.y,fmaf(xq2.z,y2.z,fmaf(xq2.w,y2.w,acc))));
        acc=fmaf(xq3.x,y3.x,fmaf(xq3.y,y3.y,fmaf(xq3.z,y3.z,fmaf(xq3.w,y3.w,acc))));
        acc=fmaf(xq4.x,y4.x,fmaf(xq4.y,y4.y,fmaf(xq4.z,y4.z,fmaf(xq4.w,y4.w,acc))));
        Mr[k]=acc;
      }
    }
  }
  if(rowAct){
    const float xni=ws[WS_XN+b*256+i];
    #pragma unroll
    for(int k=0;k<25;k++) Mr[k]=xni+ynL[2*k+h]-SCf*Mr[k];
  }
  { // transpose into MT4 [unit][col] (rows>=len write 0: finite; masked via AfP=-1e9)
    #pragma unroll
    for(int k=0;k<25;k++){
      ((float*)&MT4[(i>>2)*52+(2*k+h)])[i&3]=Mr[k];
    }
  }
  __syncthreads();
  float Fi=0.f, Gj=0.f;
  const bool wAct=((w<<5)<len);
  const bool gAct=wAct&&(l<50);
  const float* Gh=GLbp[h];
  #pragma unroll 1
  for(int it=0; it<51; ++it){
    float smf=0.f;
    if(wAct){
      // ---- f: row i over 25 cols (regs + GLbp[h] float4 broadcasts) ----
      float m0=MNEG,m1=MNEG,m2=MNEG,m3=MNEG;
      #pragma unroll
      for(int k4=0;k4<6;k4++){
        const float4 gv=*(const float4*)&Gh[4*k4];
        m0=fmaxf(m0,gv.x-Mr[4*k4+0]); m1=fmaxf(m1,gv.y-Mr[4*k4+1]);
        m2=fmaxf(m2,gv.z-Mr[4*k4+2]); m3=fmaxf(m3,gv.w-Mr[4*k4+3]);
      }
      m0=fmaxf(m0,Gh[24]-Mr[24]);
      float mf=fmaxf(fmaxf(m0,m1),fmaxf(m2,m3));
      mf=fmaxf(mf,__shfl_xor(mf,1));
      float s0=0.f,s1=0.f,s2=0.f,s3=0.f;
      #pragma unroll
      for(int k4=0;k4<6;k4++){
        const float4 gv=*(const float4*)&Gh[4*k4];
        s0+=ex2(gv.x-Mr[4*k4+0]-mf); s1+=ex2(gv.y-Mr[4*k4+1]-mf);
        s2+=ex2(gv.z-Mr[4*k4+2]-mf); s3+=ex2(gv.w-Mr[4*k4+3]-mf);
      }
      s0+=ex2(Gh[24]-Mr[24]-mf);
      float fs=(s0+s1)+(s2+s3);
      fs+=__shfl_xor(fs,1);
      smf=-(mf+lg2(fs));
      // ---- g: col l, rows [32w,32w+32) via MT4 [unit][col] ----
      if(gAct){
        const int ub=(w*8)*52+l;
        float g0=MNEG,g1=MNEG,g2=MNEG,g3=MNEG;
        #pragma unroll
        for(int r4=0;r4<8;r4++){
          const float4 mv=MT4[ub+r4*52];
          const float4 av=*(const float4*)&AfP[w*40+4*r4];
          g0=fmaxf(g0,av.x-mv.x); g1=fmaxf(g1,av.y-mv.y);
          g2=fmaxf(g2,av.z-mv.z); g3=fmaxf(g3,av.w-mv.w);
        }
        const float gm=fmaxf(fmaxf(g0,g1),fmaxf(g2,g3));
        float t0s=0.f,t1s=0.f,t2s=0.f,t3s=0.f;
        #pragma unroll
        for(int r4=0;r4<8;r4++){
          const float4 mv=MT4[ub+r4*52];
          const float4 av=*(const float4*)&AfP[w*40+4*r4];
          t0s+=ex2(av.x-mv.x-gm); t1s+=ex2(av.y-mv.y-gm);
          t2s+=ex2(av.z-mv.z-gm); t3s+=ex2(av.w-mv.w-gm);
        }
        PM[w*52+l]=gm;
        PS[w*52+l]=(t0s+t1s)+(t2s+t3s);
      }
    }
    __syncthreads();
    if(wAct){
      Fi=(it==0)?smf:0.5f*(Fi+smf);
      if(h==0) AfP[(i>>5)*40+(i&31)]=al2+Fi;   // i>=len: al2=-1e9 dominates -> exact mask
    }
    if(w==0 && l<50){                           // wave 0 combines 8 chunk-partials
      const float p0=PM[l],p1=PM[52+l],p2=PM[104+l],p3=PM[156+l];
      const float p4=PM[208+l],p5=PM[260+l],p6=PM[312+l],p7=PM[364+l];
      const float mm=fmaxf(fmaxf(fmaxf(p0,p1),fmaxf(p2,p3)),fmaxf(fmaxf(p4,p5),fmaxf(p6,p7)));
      float ssv=PS[l]*ex2(p0-mm)+PS[52+l]*ex2(p1-mm)
               +PS[104+l]*ex2(p2-mm)+PS[156+l]*ex2(p3-mm)
               +PS[208+l]*ex2(p4-mm)+PS[260+l]*ex2(p5-mm)
               +PS[312+l]*ex2(p6-mm)+PS[364+l]*ex2(p7-mm);
      const float smg=-(mm+lg2(ssv));
      Gj=(it==0)?smg:0.5f*(Gj+smg);
      GLbp[l&1][l>>1]=BL2f+Gj;
    }
    __syncthreads();
  }
  // S[b,c] = ELN*(sum_i a_i F_i + 0.02*sum_j G_j)
  float cv=(h==0 && rowAct)?(weight[(size_t)b*256+i]*Fi):0.f;
  #pragma unroll
  for(int off=1;off<64;off<<=1) cv+=__shfl_xor(cv,off);
  if(l==0) red[w]=cv;
  if(w==0){
    float gv=(l<50)?Gj:0.f;
    #pragma unroll
    for(int off=1;off<64;off<<=1) gv+=__shfl_xor(gv,off);
    if(l==0) red[8]=gv;
  }
  __syncthreads();
  if(t==0){
    float sa=red[0]+red[1]+red[2]+red[3]+red[4]+red[5]+red[6]+red[7];
    ws[WS_S+b*NC+c]=ELNf*(sa+0.02f*red[8]);
  }
}

// ---------------- k_d: margin loss + mean ----------------
__global__ __launch_bounds__(256) void k_d(const int* __restrict__ grade,
                                           const float* __restrict__ ws,
                                           float* __restrict__ out){
  __shared__ float red[4];
  const int t=threadIdx.x;
  const int g=grade[t];
  const float pa=ws[WS_PA+t];
  const float d0=ws[WS_S+t*NC+0]-pa-ws[WS_QC+0];
  const float d1=ws[WS_S+t*NC+1]-pa-ws[WS_QC+1];
  const float d2=ws[WS_S+t*NC+2]-pa-ws[WS_QC+2];
  const float d3=ws[WS_S+t*NC+3]-pa-ws[WS_QC+3];
  const float d4=ws[WS_S+t*NC+4]-pa-ws[WS_QC+4];
  const float pos=(g==0)?d0:(g==1)?d1:(g==2)?d2:(g==3)?d3:d4;
  float loss=0.f;
  if(g!=0) loss+=fmaxf(0.f,pos-d0+10.f);
  if(g!=1) loss+=fmaxf(0.f,pos-d1+10.f);
  if(g!=2) loss+=fmaxf(0.f,pos-d2+10.f);
  if(g!=3) loss+=fmaxf(0.f,pos-d3+10.f);
  if(g!=4) loss+=fmaxf(0.f,pos-d4+10.f);
  loss*=0.2f;
  #pragma unroll
  for(int off=1;off<64;off<<=1) loss+=__shfl_xor(loss,off);
  if((t&63)==0) red[t>>6]=loss;
  __syncthreads();
  if(t==0) out[0]=(red[0]+red[1]+red[2]+red[3])*(1.f/256.f);
}

extern "C" void kernel_launch(void* const* d_in, const int* in_sizes, int n_in,
                              void* d_out, int out_size, void* d_ws, size_t ws_size,
                              hipStream_t stream){
  (void)in_sizes;(void)n_in;(void)out_size;(void)ws_size;
  const float* anchor=(const float*)d_in[0];
  const float* weight=(const float*)d_in[1];
  const float* t0    =(const float*)d_in[2];
  const int*   lena  =(const int*)d_in[4];
  const int*   grade =(const int*)d_in[5];
  float* ws=(float*)d_ws;
  float* out=(float*)d_out;
  k_pre<<<257,256,0,stream>>>(anchor,weight,t0,lena,ws);
  k_ab <<<261,1024,0,stream>>>(anchor,weight,t0,lena,ws);
  k_c  <<<1280,512,0,stream>>>(anchor,weight,t0,lena,ws);
  k_d  <<<1,256,0,stream>>>(grade,ws,out);
}